// Round 14
// baseline (116.522 us; speedup 1.0000x reference)
//
#include <hip/hip_runtime.h>

#define N_NODES 50000
#define N_EDGES 500000
#define NQ (N_EDGES / 4)   // 125000 edge quads
#define D 128
#define NBUCK 391          // bucket = dst >> 7 (128 nodes per bucket)
#define BN 128             // nodes per bucket
#define REG 2048           // record capacity per bucket (mean ~1279, +20 sigma)
#define GEMVB 3125         // gemv blocks in mid kernel (16 nodes x 512 thr each)
#define NWB 245            // writer blocks (512 quads = 2048 edges each)
#define FXS 4194304.0f     // 2^22 fixed-point scale for weighted degree
#define AXS 2097152.0f     // 2^21 fixed-point scale for message sums (|sum| < 1024)

typedef unsigned long long u64;

// ---- D1: compact bucket build (finer buckets, full-CU writer spread) + weight
// collapse in the extra block. Per writer block (2048 edges): LDS histogram ->
// one reserving global atomic per non-empty bucket (~96K total) -> scattered
// 8B records (runs of ~10).
// Record: hi = w bits, lo = (dst&127)<<16 | src    (src < 2^16: N_NODES = 50000)
__global__ __launch_bounds__(512) void bucket_kernel(const int* __restrict__ src,
                                                     const int* __restrict__ dst,
                                                     const float* __restrict__ ew,
                                                     const float* __restrict__ W1,
                                                     const float* __restrict__ W2,
                                                     const float* __restrict__ b1,
                                                     const float* __restrict__ b2,
                                                     const float* __restrict__ Wf,
                                                     const float* __restrict__ bf,
                                                     unsigned* __restrict__ alloc,
                                                     u64* __restrict__ recs,
                                                     float* __restrict__ v,
                                                     float* __restrict__ consts) {
    const int t = threadIdx.x;
    if ((int)blockIdx.x == NWB) {                 // weight collapse (v, c1, c0)
        __shared__ float u[D];
        if (t < D) {
            float a = 0.f;
#pragma unroll 8
            for (int j = 0; j < D; ++j) a += W2[t * D + j] * Wf[j];
            u[t] = a;                             // u = W2 @ Wf
        }
        __syncthreads();
        if (t < D) {
            float a = 0.f;
#pragma unroll 8
            for (int k = 0; k < D; ++k) a += W1[t * D + k] * u[k];
            v[t] = a;                             // v = W1 @ u
        }
        if (t == 0) {
            float c = 0.f;
            for (int k = 0; k < D; ++k) c += b1[k] * u[k];
            consts[0] = c;                        // c1 = b1 . u
        } else if (t == 1) {
            float c = bf[0];
            for (int k = 0; k < D; ++k) c += b2[k] * Wf[k];
            consts[1] = c;                        // c0 = b2 . Wf + bf
        }
        return;
    }
    __shared__ unsigned hist[NBUCK];
    if (t < NBUCK) hist[t] = 0u;
    __syncthreads();
    const int q = blockIdx.x * 512 + t;           // one quad (4 edges) per thread
    const bool act = q < NQ;
    int4 d4, s4; float4 w4;
    if (act) {
        d4 = ((const int4*)dst)[q];
        s4 = ((const int4*)src)[q];
        w4 = ((const float4*)ew)[q];
        atomicAdd(&hist[d4.x >> 7], 1u); atomicAdd(&hist[d4.y >> 7], 1u);
        atomicAdd(&hist[d4.z >> 7], 1u); atomicAdd(&hist[d4.w >> 7], 1u);
    }
    __syncthreads();
    if (t < NBUCK) {
        unsigned c = hist[t];
        hist[t] = c ? atomicAdd(&alloc[t], c) : 0u;   // run base -> block cursor
    }
    __syncthreads();
#define PLACE(dd, ss, ww)                                                        \
    {   int bkt = (dd) >> 7;                                                     \
        unsigned p = atomicAdd(&hist[bkt], 1u);                                  \
        if (p < REG)                                                             \
            recs[(size_t)bkt * REG + p] =                                        \
                ((u64)__float_as_uint(ww) << 32) |                               \
                ((unsigned)((dd) & 127) << 16) | (unsigned)(ss);                 \
    }
    if (act) {
        PLACE(d4.x, s4.x, w4.x) PLACE(d4.y, s4.y, w4.y)
        PLACE(d4.z, s4.z, w4.z) PLACE(d4.w, s4.w, w4.w)
    }
#undef PLACE
}

// ---- D2: block-specialized mid kernel.
// blocks [0, GEMVB): traw[n] = x[n,:].v   (full-grid BW stream, 16 nodes/block)
// blocks [GEMVB, GEMVB+NBUCK): per-bucket weighted degree (paired 16B record
//                              stream, all lanes) -> dinv[n]
__global__ __launch_bounds__(512) void mid_kernel(const float* __restrict__ x,
                                                  const float* __restrict__ v,
                                                  const u64* __restrict__ recs,
                                                  const unsigned* __restrict__ alloc,
                                                  float* __restrict__ traw,
                                                  float* __restrict__ dinv) {
    const int t = threadIdx.x;
    const int bid = blockIdx.x;
    if (bid < GEMVB) {
        __shared__ float vs[D];
        if (t < D) vs[t] = v[t];
        __syncthreads();
        const int l = t & 31;
        const int n = bid * 16 + (t >> 5);        // 3125*16 = 50000, exact
        float4 xv = ((const float4*)(x + (size_t)n * D))[l];
        float a = xv.x * vs[l * 4] + xv.y * vs[l * 4 + 1] +
                  xv.z * vs[l * 4 + 2] + xv.w * vs[l * 4 + 3];
#pragma unroll
        for (int off = 16; off > 0; off >>= 1) a += __shfl_xor(a, off);
        if (l == 0) traw[n] = a;
        return;
    }
    const int b = bid - GEMVB;
    __shared__ unsigned ws[BN];
    if (t < BN) ws[t] = 0u;
    __syncthreads();
    unsigned total = alloc[b];
    if (total > REG) total = REG;
    const u64* rb = recs + (size_t)b * REG;
    const unsigned npair = total >> 1;
    for (unsigned i = t; i < npair; i += 512) {   // 16B paired loads, all lanes
        ulonglong2 pr = ((const ulonglong2*)rb)[i];
        float w0 = __uint_as_float((unsigned)(pr.x >> 32));
        atomicAdd(&ws[((unsigned)pr.x >> 16) & 0x7fu], __float2uint_rn(w0 * FXS));
        float w1 = __uint_as_float((unsigned)(pr.y >> 32));
        atomicAdd(&ws[((unsigned)pr.y >> 16) & 0x7fu], __float2uint_rn(w1 * FXS));
    }
    if ((total & 1u) && t == 0) {
        u64 r = rb[total - 1];
        float w = __uint_as_float((unsigned)(r >> 32));
        atomicAdd(&ws[((unsigned)r >> 16) & 0x7fu], __float2uint_rn(w * FXS));
    }
    __syncthreads();
    if (t < BN) {
        int n = b * BN + t;
        if (n < N_NODES)
            dinv[n] = rsqrtf((float)ws[t] * (1.0f / FXS) + 1.0f);
    }
}

// ---- D3: gather_s. acc[d] += w * (dinv[src]*traw[src]) in s32 fixed point (LDS);
// sw[n] = di*( di*(acc + di*traw[n]) + c1 ).  dinv/traw L2-resident (2x200 KB).
__global__ __launch_bounds__(512) void gather_s_kernel(const u64* __restrict__ recs,
                                                       const unsigned* __restrict__ alloc,
                                                       const float* __restrict__ traw,
                                                       const float* __restrict__ dinv,
                                                       const float* __restrict__ consts,
                                                       float* __restrict__ sw) {
    __shared__ int acc[BN];
    const int b = blockIdx.x, t = threadIdx.x;
    if (t < BN) acc[t] = 0;
    __syncthreads();
    unsigned total = alloc[b];
    if (total > REG) total = REG;
    const u64* rb = recs + (size_t)b * REG;
    const unsigned npair = total >> 1;
    for (unsigned i = t; i < npair; i += 512) {
        ulonglong2 pr = ((const ulonglong2*)rb)[i];
        {   unsigned lo = (unsigned)pr.x; int s = lo & 0xffff;
            float m = __uint_as_float((unsigned)(pr.x >> 32)) * dinv[s] * traw[s];
            atomicAdd(&acc[(lo >> 16) & 0x7fu], __float2int_rn(m * AXS)); }
        {   unsigned lo = (unsigned)pr.y; int s = lo & 0xffff;
            float m = __uint_as_float((unsigned)(pr.y >> 32)) * dinv[s] * traw[s];
            atomicAdd(&acc[(lo >> 16) & 0x7fu], __float2int_rn(m * AXS)); }
    }
    if ((total & 1u) && t == 0) {
        u64 r = rb[total - 1];
        unsigned lo = (unsigned)r; int s = lo & 0xffff;
        float m = __uint_as_float((unsigned)(r >> 32)) * dinv[s] * traw[s];
        atomicAdd(&acc[(lo >> 16) & 0x7fu], __float2int_rn(m * AXS));
    }
    __syncthreads();
    if (t < BN) {
        int n = b * BN + t;
        if (n < N_NODES) {
            float di = dinv[n];
            float twn = di * traw[n];
            float a = (float)acc[t] * (1.0f / AXS);
            sw[n] = di * (di * (a + twn) + consts[0]);
        }
    }
}

// ---- D4: gather_z. acc[d] += w*sw[src]; out[n] = sigmoid( di*(acc+sw[n]) + c0 )*10
__global__ __launch_bounds__(512) void gather_z_kernel(const u64* __restrict__ recs,
                                                       const unsigned* __restrict__ alloc,
                                                       const float* __restrict__ sw,
                                                       const float* __restrict__ dinv,
                                                       const float* __restrict__ consts,
                                                       float* __restrict__ out) {
    __shared__ int acc[BN];
    const int b = blockIdx.x, t = threadIdx.x;
    if (t < BN) acc[t] = 0;
    __syncthreads();
    unsigned total = alloc[b];
    if (total > REG) total = REG;
    const u64* rb = recs + (size_t)b * REG;
    const unsigned npair = total >> 1;
    for (unsigned i = t; i < npair; i += 512) {
        ulonglong2 pr = ((const ulonglong2*)rb)[i];
        {   unsigned lo = (unsigned)pr.x;
            float m = __uint_as_float((unsigned)(pr.x >> 32)) * sw[lo & 0xffffu];
            atomicAdd(&acc[(lo >> 16) & 0x7fu], __float2int_rn(m * AXS)); }
        {   unsigned lo = (unsigned)pr.y;
            float m = __uint_as_float((unsigned)(pr.y >> 32)) * sw[lo & 0xffffu];
            atomicAdd(&acc[(lo >> 16) & 0x7fu], __float2int_rn(m * AXS)); }
    }
    if ((total & 1u) && t == 0) {
        u64 r = rb[total - 1];
        unsigned lo = (unsigned)r;
        float m = __uint_as_float((unsigned)(r >> 32)) * sw[lo & 0xffffu];
        atomicAdd(&acc[(lo >> 16) & 0x7fu], __float2int_rn(m * AXS));
    }
    __syncthreads();
    if (t < BN) {
        int n = b * BN + t;
        if (n < N_NODES) {
            float di = dinv[n];
            float a = (float)acc[t] * (1.0f / AXS);
            float z = di * (a + sw[n]) + consts[1];
            out[n] = 10.0f / (1.0f + expf(-z));
        }
    }
}

extern "C" void kernel_launch(void* const* d_in, const int* in_sizes, int n_in,
                              void* d_out, int out_size, void* d_ws, size_t ws_size,
                              hipStream_t stream) {
    const float* x  = (const float*)d_in[0];
    const int*   ei = (const int*)d_in[1];
    const float* ew = (const float*)d_in[2];
    const float* W1 = (const float*)d_in[3];
    const float* b1 = (const float*)d_in[4];
    const float* W2 = (const float*)d_in[5];
    const float* b2 = (const float*)d_in[6];
    const float* Wf = (const float*)d_in[7];
    const float* bf = (const float*)d_in[8];
    const int* srcv = ei;
    const int* dstv = ei + N_EDGES;
    float* out = (float*)d_out;

    char* p = (char*)d_ws;
    auto alloc_ws = [&](size_t bytes) { void* r = (void*)p; p += (bytes + 255) & ~(size_t)255; return r; };
    unsigned* alloc  = (unsigned*)alloc_ws(512 * 4);
    u64*      recs   = (u64*)alloc_ws((size_t)NBUCK * REG * 8);   // 6.4 MB compact
    float*    traw   = (float*)alloc_ws(N_NODES * 4);
    float*    dinv   = (float*)alloc_ws(N_NODES * 4);
    float*    sw     = (float*)alloc_ws(N_NODES * 4);
    float*    v      = (float*)alloc_ws(D * 4);
    float*    consts = (float*)alloc_ws(2 * 4);

    // tiny zero of the bucket allocators (1.6 KB)
    hipMemsetAsync(alloc, 0, NBUCK * 4, stream);

    // D1: compact bucket build (245 writer blocks) + weight collapse (extra block)
    bucket_kernel<<<NWB + 1, 512, 0, stream>>>(srcv, dstv, ew, W1, W2, b1, b2, Wf, bf,
                                               alloc, recs, v, consts);

    // D2: gemv (full grid) | per-bucket degree (391 blocks) -> traw, dinv
    mid_kernel<<<GEMVB + NBUCK, 512, 0, stream>>>(x, v, recs, alloc, traw, dinv);

    // D3, D4: the two aggregation layers (391 blocks each, paired 16B streams)
    gather_s_kernel<<<NBUCK, 512, 0, stream>>>(recs, alloc, traw, dinv, consts, sw);
    gather_z_kernel<<<NBUCK, 512, 0, stream>>>(recs, alloc, sw, dinv, consts, out);
}

// Round 15
// 114.316 us; speedup vs baseline: 1.0193x; 1.0193x over previous
//
#include <hip/hip_runtime.h>

#define N_NODES 50000
#define N_EDGES 500000
#define NQ (N_EDGES / 4)   // 125000 edge quads
#define D 128
#define NBUCK 196          // bucket = dst >> 8 (256 nodes per bucket)
#define BN 256             // nodes per bucket
#define REG 4096           // record capacity per bucket (mean 2551, +30 sigma)
#define GEMVB 3125         // gemv blocks in mid kernel (16 nodes x 512 thr each)
#define FXS 4194304.0f     // 2^22 fixed-point scale for weighted degree
#define AXS 2097152.0f     // 2^21 fixed-point scale for message sums (|sum| < 1024)

typedef unsigned long long u64;

// ---- D1: bucket build (compact, reserving-atomic) + weight collapse in the
// extra block. Per writer block (4096 edges): LDS histogram -> one reserving
// global atomic per bucket (~24K total) -> scattered 8B records (runs of ~21).
// Record: hi = w bits, lo = (dst&255)<<16 | src    (src < 2^16: N_NODES = 50000)
__global__ __launch_bounds__(512) void bucket_kernel(const int* __restrict__ src,
                                                     const int* __restrict__ dst,
                                                     const float* __restrict__ ew,
                                                     const float* __restrict__ W1,
                                                     const float* __restrict__ W2,
                                                     const float* __restrict__ b1,
                                                     const float* __restrict__ b2,
                                                     const float* __restrict__ Wf,
                                                     const float* __restrict__ bf,
                                                     unsigned* __restrict__ alloc,
                                                     u64* __restrict__ recs,
                                                     float* __restrict__ v,
                                                     float* __restrict__ consts,
                                                     int nwb) {
    const int t = threadIdx.x;
    if ((int)blockIdx.x == nwb) {                 // weight collapse (v, c1, c0)
        __shared__ float u[D];
        if (t < D) {
            float a = 0.f;
#pragma unroll 8
            for (int j = 0; j < D; ++j) a += W2[t * D + j] * Wf[j];
            u[t] = a;                             // u = W2 @ Wf
        }
        __syncthreads();
        if (t < D) {
            float a = 0.f;
#pragma unroll 8
            for (int k = 0; k < D; ++k) a += W1[t * D + k] * u[k];
            v[t] = a;                             // v = W1 @ u
        }
        if (t == 0) {
            float c = 0.f;
            for (int k = 0; k < D; ++k) c += b1[k] * u[k];
            consts[0] = c;                        // c1 = b1 . u
        } else if (t == 1) {
            float c = bf[0];
            for (int k = 0; k < D; ++k) c += b2[k] * Wf[k];
            consts[1] = c;                        // c0 = b2 . Wf + bf
        }
        return;
    }
    __shared__ unsigned hist[NBUCK];
    if (t < NBUCK) hist[t] = 0u;
    __syncthreads();
    const int q0 = blockIdx.x * 1024 + t;
    const int q1 = q0 + 512;
    int4 dA, sA, dB, sB; float4 wA, wB;
    const bool aA = q0 < NQ, aB = q1 < NQ;
    if (aA) {
        dA = ((const int4*)dst)[q0]; sA = ((const int4*)src)[q0]; wA = ((const float4*)ew)[q0];
        atomicAdd(&hist[dA.x >> 8], 1u); atomicAdd(&hist[dA.y >> 8], 1u);
        atomicAdd(&hist[dA.z >> 8], 1u); atomicAdd(&hist[dA.w >> 8], 1u);
    }
    if (aB) {
        dB = ((const int4*)dst)[q1]; sB = ((const int4*)src)[q1]; wB = ((const float4*)ew)[q1];
        atomicAdd(&hist[dB.x >> 8], 1u); atomicAdd(&hist[dB.y >> 8], 1u);
        atomicAdd(&hist[dB.z >> 8], 1u); atomicAdd(&hist[dB.w >> 8], 1u);
    }
    __syncthreads();
    if (t < NBUCK) hist[t] = atomicAdd(&alloc[t], hist[t]);   // run base -> cursor
    __syncthreads();
#define PLACE(dd, ss, ww)                                                        \
    {   int bkt = (dd) >> 8;                                                     \
        unsigned p = atomicAdd(&hist[bkt], 1u);                                  \
        if (p < REG)                                                             \
            recs[(size_t)bkt * REG + p] =                                        \
                ((u64)__float_as_uint(ww) << 32) |                               \
                ((unsigned)((dd) & 255) << 16) | (unsigned)(ss);                 \
    }
    if (aA) { PLACE(dA.x, sA.x, wA.x) PLACE(dA.y, sA.y, wA.y)
              PLACE(dA.z, sA.z, wA.z) PLACE(dA.w, sA.w, wA.w) }
    if (aB) { PLACE(dB.x, sB.x, wB.x) PLACE(dB.y, sB.y, wB.y)
              PLACE(dB.z, sB.z, wB.z) PLACE(dB.w, sB.w, wB.w) }
#undef PLACE
}

// ---- D2: block-specialized mid kernel.
// blocks [0, GEMVB): traw[n] = x[n,:].v   (full-grid BW stream, 16 nodes/block)
// blocks [GEMVB, GEMVB+NBUCK): per-bucket weighted degree from compact records
//                              (all-lane streaming loop) -> dinv[n]
__global__ __launch_bounds__(512) void mid_kernel(const float* __restrict__ x,
                                                  const float* __restrict__ v,
                                                  const u64* __restrict__ recs,
                                                  const unsigned* __restrict__ alloc,
                                                  float* __restrict__ traw,
                                                  float* __restrict__ dinv) {
    const int t = threadIdx.x;
    const int bid = blockIdx.x;
    if (bid < GEMVB) {
        __shared__ float vs[D];
        if (t < D) vs[t] = v[t];
        __syncthreads();
        const int l = t & 31;
        const int n = bid * 16 + (t >> 5);        // 3125*16 = 50000, exact
        float4 xv = ((const float4*)(x + (size_t)n * D))[l];
        float a = xv.x * vs[l * 4] + xv.y * vs[l * 4 + 1] +
                  xv.z * vs[l * 4 + 2] + xv.w * vs[l * 4 + 3];
#pragma unroll
        for (int off = 16; off > 0; off >>= 1) a += __shfl_xor(a, off);
        if (l == 0) traw[n] = a;
        return;
    }
    const int b = bid - GEMVB;
    __shared__ unsigned ws[BN];
    if (t < BN) ws[t] = 0u;
    __syncthreads();
    unsigned total = alloc[b];
    if (total > REG) total = REG;
    const u64* rb = recs + (size_t)b * REG;
    for (unsigned i = t; i < total; i += 512) {   // all 512 lanes active
        u64 r = rb[i];
        float w = __uint_as_float((unsigned)(r >> 32));
        atomicAdd(&ws[((unsigned)r >> 16) & 0xffu], __float2uint_rn(w * FXS));
    }
    __syncthreads();
    if (t < BN) {
        int n = b * BN + t;
        if (n < N_NODES)
            dinv[n] = rsqrtf((float)ws[t] * (1.0f / FXS) + 1.0f);
    }
}

// ---- D3: gather_s. acc[d] += w * (dinv[src]*traw[src]) in s32 fixed point (LDS);
// sw[n] = di*( di*(acc + di*traw[n]) + c1 ).  dinv/traw are L2-resident 200 KB.
__global__ __launch_bounds__(512) void gather_s_kernel(const u64* __restrict__ recs,
                                                       const unsigned* __restrict__ alloc,
                                                       const float* __restrict__ traw,
                                                       const float* __restrict__ dinv,
                                                       const float* __restrict__ consts,
                                                       float* __restrict__ sw) {
    __shared__ int acc[BN];
    const int b = blockIdx.x, t = threadIdx.x;
    if (t < BN) acc[t] = 0;
    __syncthreads();
    unsigned total = alloc[b];
    if (total > REG) total = REG;
    const u64* rb = recs + (size_t)b * REG;
    for (unsigned i = t; i < total; i += 512) {
        u64 r = rb[i];
        unsigned lo = (unsigned)r;
        int s = lo & 0xffff;
        float m = __uint_as_float((unsigned)(r >> 32)) * dinv[s] * traw[s];
        atomicAdd(&acc[(lo >> 16) & 0xffu], __float2int_rn(m * AXS));
    }
    __syncthreads();
    if (t < BN) {
        int n = b * BN + t;
        if (n < N_NODES) {
            float di = dinv[n];
            float twn = di * traw[n];
            float a = (float)acc[t] * (1.0f / AXS);
            sw[n] = di * (di * (a + twn) + consts[0]);
        }
    }
}

// ---- D4: gather_z. acc[d] += w*sw[src]; out[n] = sigmoid( di*(acc+sw[n]) + c0 )*10
__global__ __launch_bounds__(512) void gather_z_kernel(const u64* __restrict__ recs,
                                                       const unsigned* __restrict__ alloc,
                                                       const float* __restrict__ sw,
                                                       const float* __restrict__ dinv,
                                                       const float* __restrict__ consts,
                                                       float* __restrict__ out) {
    __shared__ int acc[BN];
    const int b = blockIdx.x, t = threadIdx.x;
    if (t < BN) acc[t] = 0;
    __syncthreads();
    unsigned total = alloc[b];
    if (total > REG) total = REG;
    const u64* rb = recs + (size_t)b * REG;
    for (unsigned i = t; i < total; i += 512) {
        u64 r = rb[i];
        unsigned lo = (unsigned)r;
        float m = __uint_as_float((unsigned)(r >> 32)) * sw[lo & 0xffffu];
        atomicAdd(&acc[(lo >> 16) & 0xffu], __float2int_rn(m * AXS));
    }
    __syncthreads();
    if (t < BN) {
        int n = b * BN + t;
        if (n < N_NODES) {
            float di = dinv[n];
            float a = (float)acc[t] * (1.0f / AXS);
            float z = di * (a + sw[n]) + consts[1];
            out[n] = 10.0f / (1.0f + expf(-z));
        }
    }
}

extern "C" void kernel_launch(void* const* d_in, const int* in_sizes, int n_in,
                              void* d_out, int out_size, void* d_ws, size_t ws_size,
                              hipStream_t stream) {
    const float* x  = (const float*)d_in[0];
    const int*   ei = (const int*)d_in[1];
    const float* ew = (const float*)d_in[2];
    const float* W1 = (const float*)d_in[3];
    const float* b1 = (const float*)d_in[4];
    const float* W2 = (const float*)d_in[5];
    const float* b2 = (const float*)d_in[6];
    const float* Wf = (const float*)d_in[7];
    const float* bf = (const float*)d_in[8];
    const int* srcv = ei;
    const int* dstv = ei + N_EDGES;
    float* out = (float*)d_out;

    char* p = (char*)d_ws;
    auto alloc_ws = [&](size_t bytes) { void* r = (void*)p; p += (bytes + 255) & ~(size_t)255; return r; };
    unsigned* alloc  = (unsigned*)alloc_ws(256 * 4);
    u64*      recs   = (u64*)alloc_ws((size_t)NBUCK * REG * 8);   // 6.4 MB compact
    float*    traw   = (float*)alloc_ws(N_NODES * 4);
    float*    dinv   = (float*)alloc_ws(N_NODES * 4);
    float*    sw     = (float*)alloc_ws(N_NODES * 4);
    float*    v      = (float*)alloc_ws(D * 4);
    float*    consts = (float*)alloc_ws(2 * 4);

    const int NWB = (NQ + 1023) / 1024;   // 123 writer blocks

    // tiny 784B zero of the bucket allocators (replaces the prep dispatch)
    hipMemsetAsync(alloc, 0, NBUCK * 4, stream);

    // D1: compact bucket build + weight collapse (extra block)
    bucket_kernel<<<NWB + 1, 512, 0, stream>>>(srcv, dstv, ew, W1, W2, b1, b2, Wf, bf,
                                               alloc, recs, v, consts, NWB);

    // D2: gemv (full grid) | per-bucket degree (compact stream) -> traw, dinv
    mid_kernel<<<GEMVB + NBUCK, 512, 0, stream>>>(x, v, recs, alloc, traw, dinv);

    // D3, D4: the two aggregation layers (compact all-lane streams)
    gather_s_kernel<<<NBUCK, 512, 0, stream>>>(recs, alloc, traw, dinv, consts, sw);
    gather_z_kernel<<<NBUCK, 512, 0, stream>>>(recs, alloc, sw, dinv, consts, out);
}